// Round 1
// baseline (185.970 us; speedup 1.0000x reference)
//
#include <hip/hip_runtime.h>

#define NBINS 64
#define NCOPIES 32
#define BLOCK 256

__global__ __launch_bounds__(BLOCK, 4) void hist_rows_kernel(
    const float* __restrict__ x, float* __restrict__ out, int ncols) {
    // 32 privatized copies of the 64-bin histogram.
    // Layout hist[bin * 32 + copy]: dword bank == copy == (tid & 31),
    // so each wave's 64 lanes alias each bank exactly 2-way (free).
    __shared__ unsigned int hist[NBINS * NCOPIES];

    const int t = threadIdx.x;
    const int row = blockIdx.x;

    for (int i = t; i < NBINS * NCOPIES; i += BLOCK) hist[i] = 0u;
    __syncthreads();

    const int copy = t & (NCOPIES - 1);
    const float vmin = -3.0f;
    const float scale = 64.0f / 6.0f;   // NBINS / (VMAX - VMIN), fp32, same as ref

    const float4* xr = (const float4*)(x + (size_t)row * (size_t)ncols);
    const int nvec = ncols >> 2;  // 2048 float4 per row

    for (int i = t; i < nvec; i += BLOCK) {
        float4 v = xr[i];
        float f0 = (v.x - vmin) * scale;
        float f1 = (v.y - vmin) * scale;
        float f2 = (v.z - vmin) * scale;
        float f3 = (v.w - vmin) * scale;
        int b0 = (int)floorf(f0);
        int b1 = (int)floorf(f1);
        int b2 = (int)floorf(f2);
        int b3 = (int)floorf(f3);
        b0 = min(max(b0, 0), NBINS - 1);
        b1 = min(max(b1, 0), NBINS - 1);
        b2 = min(max(b2, 0), NBINS - 1);
        b3 = min(max(b3, 0), NBINS - 1);
        atomicAdd(&hist[b0 * NCOPIES + copy], 1u);
        atomicAdd(&hist[b1 * NCOPIES + copy], 1u);
        atomicAdd(&hist[b2 * NCOPIES + copy], 1u);
        atomicAdd(&hist[b3 * NCOPIES + copy], 1u);
    }
    __syncthreads();

    // Reduce the 32 copies; threads 0..63 each own one bin.
    if (t < NBINS) {
        unsigned int s = 0;
        #pragma unroll
        for (int c = 0; c < NCOPIES; ++c) s += hist[t * NCOPIES + c];
        const float inv = 1.0f / (float)ncols;   // exact for ncols = 8192
        out[(size_t)row * NBINS + t] = (float)s * inv;
    }
}

extern "C" void kernel_launch(void* const* d_in, const int* in_sizes, int n_in,
                              void* d_out, int out_size, void* d_ws, size_t ws_size,
                              hipStream_t stream) {
    const float* x = (const float*)d_in[0];
    float* out = (float*)d_out;
    const int nrows = out_size / NBINS;          // 4096
    const int ncols = in_sizes[0] / nrows;       // 8192
    hist_rows_kernel<<<nrows, BLOCK, 0, stream>>>(x, out, ncols);
}

// Round 2
// 185.885 us; speedup vs baseline: 1.0005x; 1.0005x over previous
//
#include <hip/hip_runtime.h>

#define NBINS 64
#define NCOPIES 64          // one copy per lane of a wave -> zero intra-wave same-address atomics
#define BLOCK 256
#define UNROLL 8            // 8 float4 loads in flight per thread

__global__ __launch_bounds__(BLOCK, 4) void hist_rows_kernel(
    const float* __restrict__ x, float* __restrict__ out, int ncols) {
    // hist[bin*64 + copy]; copy = tid & 63.
    // Atomic address per lane = bin*64 + lane -> unique within a wave (no RMW serialization).
    // Bank = copy % 32 -> exactly 2-way aliasing across 64 lanes (free, m136).
    __shared__ unsigned int hist[NBINS * NCOPIES];

    const int t = threadIdx.x;
    const int row = blockIdx.x;

    #pragma unroll
    for (int i = t; i < NBINS * NCOPIES; i += BLOCK) hist[i] = 0u;
    __syncthreads();

    const int copy = t & (NCOPIES - 1);
    const float vmin = -3.0f;
    const float scale = 64.0f / 6.0f;   // fp32, same sub-then-mul order as reference

    const float4* xr = (const float4*)(x + (size_t)row * (size_t)ncols);
    const int nvec = ncols >> 2;

    int base = 0;
    for (; base + UNROLL * BLOCK <= nvec; base += UNROLL * BLOCK) {
        float4 buf[UNROLL];
        #pragma unroll
        for (int k = 0; k < UNROLL; ++k) buf[k] = xr[base + k * BLOCK + t];
        #pragma unroll
        for (int k = 0; k < UNROLL; ++k) {
            float4 v = buf[k];
            // clamp-in-float then trunc == floor+int-clamp for all non-NaN inputs
            float f0 = __builtin_amdgcn_fmed3f((v.x - vmin) * scale, 0.0f, 63.0f);
            float f1 = __builtin_amdgcn_fmed3f((v.y - vmin) * scale, 0.0f, 63.0f);
            float f2 = __builtin_amdgcn_fmed3f((v.z - vmin) * scale, 0.0f, 63.0f);
            float f3 = __builtin_amdgcn_fmed3f((v.w - vmin) * scale, 0.0f, 63.0f);
            int b0 = (int)f0, b1 = (int)f1, b2 = (int)f2, b3 = (int)f3;
            atomicAdd(&hist[b0 * NCOPIES + copy], 1u);
            atomicAdd(&hist[b1 * NCOPIES + copy], 1u);
            atomicAdd(&hist[b2 * NCOPIES + copy], 1u);
            atomicAdd(&hist[b3 * NCOPIES + copy], 1u);
        }
    }
    // remainder (not taken for ncols = 8192)
    for (int i = base + t; i < nvec; i += BLOCK) {
        float4 v = xr[i];
        float f0 = __builtin_amdgcn_fmed3f((v.x - vmin) * scale, 0.0f, 63.0f);
        float f1 = __builtin_amdgcn_fmed3f((v.y - vmin) * scale, 0.0f, 63.0f);
        float f2 = __builtin_amdgcn_fmed3f((v.z - vmin) * scale, 0.0f, 63.0f);
        float f3 = __builtin_amdgcn_fmed3f((v.w - vmin) * scale, 0.0f, 63.0f);
        atomicAdd(&hist[(int)f0 * NCOPIES + copy], 1u);
        atomicAdd(&hist[(int)f1 * NCOPIES + copy], 1u);
        atomicAdd(&hist[(int)f2 * NCOPIES + copy], 1u);
        atomicAdd(&hist[(int)f3 * NCOPIES + copy], 1u);
    }
    __syncthreads();

    // Reduce 64 copies per bin; stagger start so lane t's reads land on
    // rotating banks: addr = t*64 + (c+t)&63 -> bank (c+t)%32, 2-way across the wave.
    if (t < NBINS) {
        unsigned int s = 0;
        #pragma unroll
        for (int c = 0; c < NCOPIES; ++c)
            s += hist[t * NCOPIES + ((c + t) & (NCOPIES - 1))];
        const float inv = 1.0f / (float)ncols;
        out[(size_t)row * NBINS + t] = (float)s * inv;
    }
}

extern "C" void kernel_launch(void* const* d_in, const int* in_sizes, int n_in,
                              void* d_out, int out_size, void* d_ws, size_t ws_size,
                              hipStream_t stream) {
    const float* x = (const float*)d_in[0];
    float* out = (float*)d_out;
    const int nrows = out_size / NBINS;          // 4096
    const int ncols = in_sizes[0] / nrows;       // 8192
    hist_rows_kernel<<<nrows, BLOCK, 0, stream>>>(x, out, ncols);
}

// Round 3
// 184.874 us; speedup vs baseline: 1.0059x; 1.0055x over previous
//
#include <hip/hip_runtime.h>

#define NBINS 64
#define NCOPIES 64          // one copy per lane of a wave -> zero intra-wave same-address atomics
#define BLOCK 256
#define UNROLL 8            // 8 float4 loads in flight per thread

// (256,8): 8 waves/SIMD -> 8 blocks/CU resident (LDS 8x16KB=128KB <= 160KB),
// doubling outstanding global loads vs (256,4). Kernel is pure-streaming HBM-bound.
__global__ __launch_bounds__(BLOCK, 8) void hist_rows_kernel(
    const float* __restrict__ x, float* __restrict__ out, int ncols) {
    // hist[bin*64 + copy]; copy = tid & 63.
    // Atomic address per lane = bin*64 + lane -> unique within a wave (no RMW serialization).
    // Bank = copy % 32 -> exactly 2-way aliasing across 64 lanes (free, m136).
    __shared__ unsigned int hist[NBINS * NCOPIES];

    const int t = threadIdx.x;
    const int row = blockIdx.x;

    #pragma unroll
    for (int i = t; i < NBINS * NCOPIES; i += BLOCK) hist[i] = 0u;
    __syncthreads();

    const int copy = t & (NCOPIES - 1);
    const float vmin = -3.0f;
    const float scale = 64.0f / 6.0f;   // fp32, same sub-then-mul order as reference

    const float4* xr = (const float4*)(x + (size_t)row * (size_t)ncols);
    const int nvec = ncols >> 2;

    int base = 0;
    for (; base + UNROLL * BLOCK <= nvec; base += UNROLL * BLOCK) {
        float4 buf[UNROLL];
        #pragma unroll
        for (int k = 0; k < UNROLL; ++k) buf[k] = xr[base + k * BLOCK + t];
        #pragma unroll
        for (int k = 0; k < UNROLL; ++k) {
            float4 v = buf[k];
            // clamp-in-float then trunc == floor+int-clamp for all non-NaN inputs
            float f0 = __builtin_amdgcn_fmed3f((v.x - vmin) * scale, 0.0f, 63.0f);
            float f1 = __builtin_amdgcn_fmed3f((v.y - vmin) * scale, 0.0f, 63.0f);
            float f2 = __builtin_amdgcn_fmed3f((v.z - vmin) * scale, 0.0f, 63.0f);
            float f3 = __builtin_amdgcn_fmed3f((v.w - vmin) * scale, 0.0f, 63.0f);
            int b0 = (int)f0, b1 = (int)f1, b2 = (int)f2, b3 = (int)f3;
            atomicAdd(&hist[b0 * NCOPIES + copy], 1u);
            atomicAdd(&hist[b1 * NCOPIES + copy], 1u);
            atomicAdd(&hist[b2 * NCOPIES + copy], 1u);
            atomicAdd(&hist[b3 * NCOPIES + copy], 1u);
        }
    }
    // remainder (not taken for ncols = 8192)
    for (int i = base + t; i < nvec; i += BLOCK) {
        float4 v = xr[i];
        float f0 = __builtin_amdgcn_fmed3f((v.x - vmin) * scale, 0.0f, 63.0f);
        float f1 = __builtin_amdgcn_fmed3f((v.y - vmin) * scale, 0.0f, 63.0f);
        float f2 = __builtin_amdgcn_fmed3f((v.z - vmin) * scale, 0.0f, 63.0f);
        float f3 = __builtin_amdgcn_fmed3f((v.w - vmin) * scale, 0.0f, 63.0f);
        atomicAdd(&hist[(int)f0 * NCOPIES + copy], 1u);
        atomicAdd(&hist[(int)f1 * NCOPIES + copy], 1u);
        atomicAdd(&hist[(int)f2 * NCOPIES + copy], 1u);
        atomicAdd(&hist[(int)f3 * NCOPIES + copy], 1u);
    }
    __syncthreads();

    // Reduce 64 copies per bin; stagger start so lane t's reads land on
    // rotating banks: addr = t*64 + (c+t)&63 -> bank (c+t)%32, 2-way across the wave.
    if (t < NBINS) {
        unsigned int s = 0;
        #pragma unroll
        for (int c = 0; c < NCOPIES; ++c)
            s += hist[t * NCOPIES + ((c + t) & (NCOPIES - 1))];
        const float inv = 1.0f / (float)ncols;
        out[(size_t)row * NBINS + t] = (float)s * inv;
    }
}

extern "C" void kernel_launch(void* const* d_in, const int* in_sizes, int n_in,
                              void* d_out, int out_size, void* d_ws, size_t ws_size,
                              hipStream_t stream) {
    const float* x = (const float*)d_in[0];
    float* out = (float*)d_out;
    const int nrows = out_size / NBINS;          // 4096
    const int ncols = in_sizes[0] / nrows;       // 8192
    hist_rows_kernel<<<nrows, BLOCK, 0, stream>>>(x, out, ncols);
}